// Round 10
// baseline (145.175 us; speedup 1.0000x reference)
//
#include <hip/hip_runtime.h>

#define N_BATCH   50000
#define N_FEATURE 128
#define DEPTH     9
#define N_TREE    200
#define N_NODE    1023
#define N_OUTPUT  8

#define BPB     64                            // batches per block (lanes)
#define WAVES   8
#define BLOCK   (WAVES * 64)                  // 512 threads
#define TPR     8                             // trees per round (1 per wave)
#define ROUNDS  (N_TREE / TPR)                // 25

// Grid: 768 monolithic chunk-blocks (3/CU x 256 CU, one clean phase) + 14
// surplus chunks shattered into 25 single-round blocks that backfill.
#define FULL_CHUNKS 768
#define NCHUNK      ((N_BATCH + BPB - 1) / BPB)     // 782
#define TAIL_CHUNKS (NCHUNK - FULL_CHUNKS)          // 14
#define TAIL_SPLIT  ROUNDS
#define TAIL_BLOCKS (TAIL_CHUNKS * TAIL_SPLIT)      // 350
#define GRID        (FULL_CHUNKS + TAIL_BLOCKS)     // 1118

// Per-wave private buffer, 1 tree (2560 B):
//   thS u32[512] @0    : UNSHIFTED copy th[0..511]; pair(n) = thS[2n+1],thS[2n+2]
//                        -> compiler fuses into one ds_read2_b32
//   fD  u16[256] @2048 : fD[n] = feat[2n+1] | feat[2n+2]<<8 (pair-packed)
// Roots live in registers (lanes 0..24 hold rounds 0..24, readlane broadcast).
#define TREE_B  2560
#define REC_B   (WAVES * TREE_B)              // 20480

__global__ __launch_bounds__(BLOCK, 6)        // 3 blocks/CU (LDS-capped), 24 waves/CU
void tree_kernel(const float* __restrict__ x,
                 const int*   __restrict__ feature,
                 const float* __restrict__ threshold,
                 const float* __restrict__ value,
                 float*       __restrict__ out)
{
    __shared__ float xt[N_FEATURE * BPB];           // 32 KB, xt[f*64+b]: bank = lane%32 (free)
    __shared__ __align__(16) char recbuf[REC_B];    // 20 KB, 8 wave-private slices

    const int tid = threadIdx.x;
    const int bid = blockIdx.x;
    const int b   = tid & 63;                       // lane = batch within chunk
    const int g   = tid >> 6;                       // wave id: tree g of each round
    char* wbuf = recbuf + g * TREE_B;

    int chunk, r0, r1; bool tail;
    if (bid < FULL_CHUNKS) { chunk = bid; r0 = 0; r1 = ROUNDS; tail = false; }
    else {
        const int t2 = bid - FULL_CHUNKS;
        chunk = FULL_CHUNKS + t2 / TAIL_SPLIT;
        r0 = t2 % TAIL_SPLIT; r1 = r0 + 1; tail = true;
    }

    // ---- per-round roots into registers: lane r (r<25) holds round r's root ----
    const int rb = (b < ROUNDS) ? b : 0;            // clamp to stay in-bounds
    const float rootThV = threshold[(size_t)(rb * TPR + g) * N_NODE];
    const int   rootFV  = feature[(size_t)(rb * TPR + g) * N_NODE];

    // incremental per-round bases
    const float* tpre  = threshold + (size_t)(r0 * TPR + g) * N_NODE;
    const int*   fpre  = feature   + (size_t)(r0 * TPR + g) * N_NODE;
    const float* vbase = value + (size_t)(r0 * TPR + g) * N_NODE * N_OUTPUT;

    // ---- prefetch round-r0 records ----
    float thrA[4], thrB[4]; int fA[4], fB[4];
    #pragma unroll
    for (int j = 0; j < 4; ++j) {
        const int e = 2 * b + 128 * j;              // th elements e, e+1 (<= 511)
        thrA[j] = tpre[e]; thrB[j] = tpre[e + 1];
        const int p = 2 * (b + 64 * j) + 1;         // feat elements p, p+1 (<= 512)
        fA[j] = fpre[p];  fB[j] = fpre[p + 1];
    }

    // ---- stage x chunk transposed into LDS (conflict-free via XOR-swizzled R) ----
    {
        const float4* x4 = (const float4*)x;
        float4* R = (float4*)recbuf;                // 16 KB alias (pre-round only)
        #pragma unroll
        for (int rr = 0; rr < 2; ++rr) {
            #pragma unroll
            for (int k = 0; k < 2; ++k) {
                const int j  = tid + k * BLOCK;
                const int bl = j >> 5, f4 = j & 31;
                const int gb = chunk * BPB + rr * 32 + bl;
                float4 v = (gb < N_BATCH) ? x4[(size_t)gb * 32 + f4]
                                          : make_float4(0.f, 0.f, 0.f, 0.f);
                R[bl * 32 + (f4 ^ bl)] = v;
            }
            __syncthreads();
            {
                const int b32 = tid & 31, fc = tid >> 5;
                const int bb = rr * 32 + b32;
                #pragma unroll
                for (int c = 0; c < 2; ++c) {
                    const int f4 = fc * 2 + c;
                    float4 v = R[b32 * 32 + (f4 ^ b32)];
                    xt[(f4 * 4 + 0) * BPB + bb] = v.x;
                    xt[(f4 * 4 + 1) * BPB + bb] = v.y;
                    xt[(f4 * 4 + 2) * BPB + bb] = v.z;
                    xt[(f4 * 4 + 3) * BPB + bb] = v.w;
                }
            }
            __syncthreads();
        }
    }
    // No block barriers until the final reduction; each wave owns wbuf,
    // ordered by its own lgkmcnt waits.

    float acc[N_OUTPUT];
    #pragma unroll
    for (int o = 0; o < N_OUTPUT; ++o) acc[o] = 0.f;

    float*          thS = (float*)wbuf;
    unsigned short* fD  = (unsigned short*)(wbuf + 2048);

    for (int r = r0; r < r1; ++r) {
        __asm__ volatile("s_waitcnt lgkmcnt(0)" ::: "memory");   // WAR on wbuf
        #pragma unroll
        for (int j = 0; j < 4; ++j) {               // 4 ds_write_b64 + 4 ds_write_b16
            ((float2*)thS)[b + 64 * j] = make_float2(thrA[j], thrB[j]);
            fD[b + 64 * j] = (unsigned short)((fA[j] & 255) | ((fB[j] & 255) << 8));
        }
        __asm__ volatile("s_waitcnt lgkmcnt(0)" ::: "memory");   // RAW visibility

        if (r + 1 < r1) {                           // prefetch next round
            const float* tn = tpre + TPR * N_NODE;
            const int*   fn = fpre + TPR * N_NODE;
            #pragma unroll
            for (int j = 0; j < 4; ++j) {
                const int e = 2 * b + 128 * j;
                thrA[j] = tn[e]; thrB[j] = tn[e + 1];
                const int p = 2 * (b + 64 * j) + 1;
                fA[j] = fn[p];  fB[j] = fn[p + 1];
            }
            tpre = tn; fpre = fn;
        }

        // ---- traverse; root from registers, next record from regs (1 LDS lat/level) ----
        int n = 0;
        float th = __int_as_float(__builtin_amdgcn_readlane(__float_as_int(rootThV), r));
        int   fv = __builtin_amdgcn_readlane(rootFV, r);
        float cx = thS[1], cy = thS[2];             // pair(0): fused ds_read2_b32
        int   k  = fD[0];
        #pragma unroll
        for (int d = 0; d < DEPTH; ++d) {
            const float xv = xt[fv * BPB + b];      // only on-chain LDS read
            const int s = (xv > th) ? 1 : 0;        // xval <= split -> left
            n = 2 * n + 1 + s;
            if (d < DEPTH - 1) {
                th = s ? cy : cx;
                fv = (k >> (s << 3)) & 255;
            }
            if (d < DEPTH - 2) {                    // speculative pair (n <= 254)
                cx = thS[2 * n + 1];                // fused ds_read2_b32
                cy = thS[2 * n + 2];
                k  = fD[n];
            }
        }
        {
            const float4* vp = (const float4*)(vbase + (size_t)n * N_OUTPUT);
            const float4 a0 = vp[0], a1 = vp[1];
            acc[0] += a0.x; acc[1] += a0.y; acc[2] += a0.z; acc[3] += a0.w;
            acc[4] += a1.x; acc[5] += a1.y; acc[6] += a1.z; acc[7] += a1.w;
        }
        vbase += (size_t)TPR * N_NODE * N_OUTPUT;
    }

    // ---- reduce 8 waves' partials (alias recbuf, stride-9 pad) ----
    __syncthreads();
    float* red = (float*)recbuf;                    // 8*576*4 = 18432 <= 20480
    {
        float* dst = red + (g * 576 + b * 9);
        #pragma unroll
        for (int o = 0; o < N_OUTPUT; ++o) dst[o] = acc[o];
    }
    __syncthreads();
    {
        const int bl = tid >> 3, o = tid & 7;       // 512 threads = 64 batches x 8 outs
        const int bg = chunk * BPB + bl;
        float s = 0.f;
        #pragma unroll
        for (int gg = 0; gg < WAVES; ++gg) s += red[gg * 576 + bl * 9 + o];
        s *= (1.0f / N_TREE);
        if (!tail) {
            out[(size_t)chunk * (BPB * N_OUTPUT) + tid] = s;   // coalesced, exactly once
        } else if (bg < N_BATCH) {
            atomicAdd(out + (size_t)bg * N_OUTPUT + o, s);
        }
    }
}

extern "C" void kernel_launch(void* const* d_in, const int* in_sizes, int n_in,
                              void* d_out, int out_size, void* d_ws, size_t ws_size,
                              hipStream_t stream) {
    const float* x         = (const float*)d_in[0];
    const int*   feature   = (const int*)d_in[1];
    const float* threshold = (const float*)d_in[2];
    const float* value     = (const float*)d_in[5];   // children implied by complete heap layout
    float* out = (float*)d_out;

    // zero only the tail-chunk region (atomic accumulation); ~27 KB
    const size_t tail_off = (size_t)FULL_CHUNKS * BPB * N_OUTPUT;
    if ((size_t)out_size > tail_off) {
        hipMemsetAsync(out + tail_off, 0, ((size_t)out_size - tail_off) * sizeof(float), stream);
    }

    tree_kernel<<<dim3(GRID), dim3(BLOCK), 0, stream>>>(x, feature, threshold, value, out);
}

// Round 11
// 140.131 us; speedup vs baseline: 1.0360x; 1.0360x over previous
//
#include <hip/hip_runtime.h>

#define N_BATCH   50000
#define N_FEATURE 128
#define DEPTH     9
#define N_TREE    200
#define N_NODE    1023
#define N_OUTPUT  8

#define BPB     64                            // batches per block (lanes)
#define WAVES   8
#define BLOCK   (WAVES * 64)                  // 512 threads
#define TPR     8                             // trees per round (1 per wave)
#define ROUNDS  (N_TREE / TPR)                // 25

// Grid: 768 monolithic chunk-blocks (3/CU x 256 CU, one clean phase) + 14
// surplus chunks shattered into 25 single-round blocks that backfill.
#define FULL_CHUNKS 768
#define NCHUNK      ((N_BATCH + BPB - 1) / BPB)     // 782
#define TAIL_CHUNKS (NCHUNK - FULL_CHUNKS)          // 14
#define TAIL_SPLIT  ROUNDS
#define TAIL_BLOCKS (TAIL_CHUNKS * TAIL_SPLIT)      // 350
#define GRID        (FULL_CHUNKS + TAIL_BLOCKS)     // 1118

// Per-wave private buffer, 1 tree (2560 B):
//   thS f32[512] @0    : SHIFTED copy thS[k]=th[k+1] (k=0..510), thS[511]=th[0];
//                        pair(n) = aligned ds_read_b64 @ 8n  (R9-proven, ~free conflicts)
//   fD  u16[256] @2048 : fD[n] = feat[2n+1] | feat[2n+2]<<8 (pair-packed);
//                        read = one aligned u16 @ 2n; staged with 4 ds_write_b16
// Roots live in registers: lane r holds round r's root, v_readlane broadcast.
#define TREE_B  2560
#define REC_B   (WAVES * TREE_B)              // 20480

__global__ __launch_bounds__(BLOCK, 6)        // 3 blocks/CU (LDS-capped), 24 waves/CU
void tree_kernel(const float* __restrict__ x,
                 const int*   __restrict__ feature,
                 const float* __restrict__ threshold,
                 const float* __restrict__ value,
                 float*       __restrict__ out)
{
    __shared__ float xt[N_FEATURE * BPB];           // 32 KB, xt[f*64+b]: bank = lane%32 (free)
    __shared__ __align__(16) char recbuf[REC_B];    // 20 KB, 8 wave-private slices

    const int tid = threadIdx.x;
    const int bid = blockIdx.x;
    const int b   = tid & 63;                       // lane = batch within chunk
    const int g   = tid >> 6;                       // wave id: tree g of each round
    char* wbuf = recbuf + g * TREE_B;

    int chunk, r0, r1; bool tail;
    if (bid < FULL_CHUNKS) { chunk = bid; r0 = 0; r1 = ROUNDS; tail = false; }
    else {
        const int t2 = bid - FULL_CHUNKS;
        chunk = FULL_CHUNKS + t2 / TAIL_SPLIT;
        r0 = t2 % TAIL_SPLIT; r1 = r0 + 1; tail = true;
    }

    // ---- roots in registers: lane r (r < 25) holds round r's root ----
    const int rb = (b < ROUNDS) ? b : 0;
    const float rootThV = threshold[(size_t)(rb * TPR + g) * N_NODE];
    const int   rootFV  = feature[(size_t)(rb * TPR + g) * N_NODE];

    // incremental per-round bases
    const float* tpre  = threshold + (size_t)(r0 * TPR + g) * N_NODE;
    const int*   fpre  = feature   + (size_t)(r0 * TPR + g) * N_NODE;
    const float* vbase = value + (size_t)(r0 * TPR + g) * N_NODE * N_OUTPUT;

    // ---- prefetch round-r0 records ----
    float thr[8]; int f0[4], f1[4];
    #pragma unroll
    for (int j = 0; j < 8; ++j) thr[j] = tpre[b + 64 * j];
    #pragma unroll
    for (int j = 0; j < 4; ++j) {                   // left/right child features of parent b+64j
        const int p = 2 * b + 128 * j + 1;          // <= 511 (+1 -> 512), in-bounds
        f0[j] = fpre[p]; f1[j] = fpre[p + 1];
    }

    // ---- stage x chunk transposed into LDS (conflict-free via XOR-swizzled R) ----
    {
        const float4* x4 = (const float4*)x;
        float4* R = (float4*)recbuf;                // 16 KB alias (pre-round only)
        #pragma unroll
        for (int rr = 0; rr < 2; ++rr) {
            #pragma unroll
            for (int k = 0; k < 2; ++k) {
                const int j  = tid + k * BLOCK;
                const int bl = j >> 5, f4 = j & 31;
                const int gb = chunk * BPB + rr * 32 + bl;
                float4 v = (gb < N_BATCH) ? x4[(size_t)gb * 32 + f4]
                                          : make_float4(0.f, 0.f, 0.f, 0.f);
                R[bl * 32 + (f4 ^ bl)] = v;
            }
            __syncthreads();
            {
                const int b32 = tid & 31, fc = tid >> 5;
                const int bb = rr * 32 + b32;
                #pragma unroll
                for (int c = 0; c < 2; ++c) {
                    const int f4 = fc * 2 + c;
                    float4 v = R[b32 * 32 + (f4 ^ b32)];
                    xt[(f4 * 4 + 0) * BPB + bb] = v.x;
                    xt[(f4 * 4 + 1) * BPB + bb] = v.y;
                    xt[(f4 * 4 + 2) * BPB + bb] = v.z;
                    xt[(f4 * 4 + 3) * BPB + bb] = v.w;
                }
            }
            __syncthreads();
        }
    }
    // No block barriers until the final reduction; each wave owns wbuf,
    // ordered by its own lgkmcnt waits.

    float acc[N_OUTPUT];
    #pragma unroll
    for (int o = 0; o < N_OUTPUT; ++o) acc[o] = 0.f;

    float*          thS = (float*)wbuf;
    unsigned short* fD  = (unsigned short*)(wbuf + 2048);

    for (int r = r0; r < r1; ++r) {
        __asm__ volatile("s_waitcnt lgkmcnt(0)" ::: "memory");   // WAR on wbuf
        #pragma unroll
        for (int j = 0; j < 8; ++j)                 // 8 conflict-free ds_write_b32
            thS[(b + 64 * j - 1) & 511] = thr[j];   // s=0 wraps to 511 (root)
        #pragma unroll
        for (int j = 0; j < 4; ++j)                 // 4 ds_write_b16 (2 lanes/dword, merged)
            fD[b + 64 * j] = (unsigned short)((f0[j] & 255) | ((f1[j] & 255) << 8));
        __asm__ volatile("s_waitcnt lgkmcnt(0)" ::: "memory");   // RAW visibility

        if (r + 1 < r1) {                           // prefetch next round
            const float* tn = tpre + TPR * N_NODE;
            const int*   fn = fpre + TPR * N_NODE;
            #pragma unroll
            for (int j = 0; j < 8; ++j) thr[j] = tn[b + 64 * j];
            #pragma unroll
            for (int j = 0; j < 4; ++j) {
                const int p = 2 * b + 128 * j + 1;
                f0[j] = fn[p]; f1[j] = fn[p + 1];
            }
            tpre = tn; fpre = fn;
        }

        // ---- traverse; root broadcast from regs, next record from regs ----
        int n = 0;
        float th = __int_as_float(__builtin_amdgcn_readlane(__float_as_int(rootThV), r));
        int   fv = __builtin_amdgcn_readlane(rootFV, r);
        float2 c = ((float2*)thS)[0];               // children of root: aligned b64
        int   k  = fD[0];
        #pragma unroll
        for (int d = 0; d < DEPTH; ++d) {
            const float xv = xt[fv * BPB + b];      // only on-chain LDS read
            const int s = (xv > th) ? 1 : 0;        // xval <= split -> left
            n = 2 * n + 1 + s;
            if (d < DEPTH - 1) {
                th = s ? c.y : c.x;
                fv = (k >> (s << 3)) & 255;
            }
            if (d < DEPTH - 2) {                    // speculative pair (n <= 254)
                c = ((float2*)thS)[n];              // aligned ds_read_b64 @ 8n
                k = fD[n];                          // aligned u16 @ 2n
            }
        }
        {
            const float4* vp = (const float4*)(vbase + (size_t)n * N_OUTPUT);
            const float4 a0 = vp[0], a1 = vp[1];
            acc[0] += a0.x; acc[1] += a0.y; acc[2] += a0.z; acc[3] += a0.w;
            acc[4] += a1.x; acc[5] += a1.y; acc[6] += a1.z; acc[7] += a1.w;
        }
        vbase += (size_t)TPR * N_NODE * N_OUTPUT;
    }

    // ---- reduce 8 waves' partials (alias recbuf, stride-9 pad) ----
    __syncthreads();
    float* red = (float*)recbuf;                    // 8*576*4 = 18432 <= 20480
    {
        float* dst = red + (g * 576 + b * 9);
        #pragma unroll
        for (int o = 0; o < N_OUTPUT; ++o) dst[o] = acc[o];
    }
    __syncthreads();
    {
        const int bl = tid >> 3, o = tid & 7;       // 512 threads = 64 batches x 8 outs
        const int bg = chunk * BPB + bl;
        float s = 0.f;
        #pragma unroll
        for (int gg = 0; gg < WAVES; ++gg) s += red[gg * 576 + bl * 9 + o];
        s *= (1.0f / N_TREE);
        if (!tail) {
            out[(size_t)chunk * (BPB * N_OUTPUT) + tid] = s;   // coalesced, exactly once
        } else if (bg < N_BATCH) {
            atomicAdd(out + (size_t)bg * N_OUTPUT + o, s);
        }
    }
}

extern "C" void kernel_launch(void* const* d_in, const int* in_sizes, int n_in,
                              void* d_out, int out_size, void* d_ws, size_t ws_size,
                              hipStream_t stream) {
    const float* x         = (const float*)d_in[0];
    const int*   feature   = (const int*)d_in[1];
    const float* threshold = (const float*)d_in[2];
    const float* value     = (const float*)d_in[5];   // children implied by complete heap layout
    float* out = (float*)d_out;

    // zero only the tail-chunk region (atomic accumulation); ~27 KB
    const size_t tail_off = (size_t)FULL_CHUNKS * BPB * N_OUTPUT;
    if ((size_t)out_size > tail_off) {
        hipMemsetAsync(out + tail_off, 0, ((size_t)out_size - tail_off) * sizeof(float), stream);
    }

    tree_kernel<<<dim3(GRID), dim3(BLOCK), 0, stream>>>(x, feature, threshold, value, out);
}

// Round 12
// 137.820 us; speedup vs baseline: 1.0534x; 1.0168x over previous
//
#include <hip/hip_runtime.h>

#define N_BATCH   50000
#define N_FEATURE 128
#define DEPTH     9
#define N_TREE    200
#define N_NODE    1023
#define N_OUTPUT  8

#define BPB     64                            // batches per block (lanes)
#define WAVES   8
#define BLOCK   (WAVES * 64)                  // 512 threads
#define TPR     8                             // trees per round (1 per wave)
#define ROUNDS  (N_TREE / TPR)                // 25

// Grid: 768 monolithic chunk-blocks (3/CU x 256 CU, one clean phase) + 14
// surplus chunks shattered into 25 single-round blocks that backfill.
#define FULL_CHUNKS 768
#define NCHUNK      ((N_BATCH + BPB - 1) / BPB)     // 782
#define TAIL_CHUNKS (NCHUNK - FULL_CHUNKS)          // 14
#define TAIL_SPLIT  ROUNDS
#define TAIL_BLOCKS (TAIL_CHUNKS * TAIL_SPLIT)      // 350
#define GRID        (FULL_CHUNKS + TAIL_BLOCKS)     // 1118

// Per-wave private buffer, 1 tree (2560 B) — EXACT R9 layout:
//   thS f32[512] @0    : shifted copy thS[k]=th[k+1] (k=0..510), thS[511]=th[0]
//                        pair(n) = aligned ds_read_b64 @ 8n
//   fS  u8 [512] @2048 : fS[k]=feat[k+1], fS[511]=root feat; fpair(n) = u16 @ 2n
// NEW vs R9: the 4 per-round root reads (root th/f, pair0, fpair0) come from
// registers preloaded once (lane r holds round r's values, v_readlane bcast).
#define TREE_B  2560
#define REC_B   (WAVES * TREE_B)              // 20480

__global__ __launch_bounds__(BLOCK, 6)        // 3 blocks/CU (LDS-capped), 24 waves/CU
void tree_kernel(const float* __restrict__ x,
                 const int*   __restrict__ feature,
                 const float* __restrict__ threshold,
                 const float* __restrict__ value,
                 float*       __restrict__ out)
{
    __shared__ float xt[N_FEATURE * BPB];           // 32 KB, xt[f*64+b]: bank = lane%32 (free)
    __shared__ __align__(16) char recbuf[REC_B];    // 20 KB, 8 wave-private slices

    const int tid = threadIdx.x;
    const int bid = blockIdx.x;
    const int b   = tid & 63;                       // lane = batch within chunk
    const int g   = tid >> 6;                       // wave id: tree g of each round
    char* wbuf = recbuf + g * TREE_B;

    int chunk, r0, r1; bool tail;
    if (bid < FULL_CHUNKS) { chunk = bid; r0 = 0; r1 = ROUNDS; tail = false; }
    else {
        const int t2 = bid - FULL_CHUNKS;
        chunk = FULL_CHUNKS + t2 / TAIL_SPLIT;
        r0 = t2 % TAIL_SPLIT; r1 = r0 + 1; tail = true;
    }

    // ---- per-round root + root-children into registers (lane r holds round r) ----
    const int    rb    = (b < ROUNDS) ? b : 0;
    const float* rbase = threshold + (size_t)(rb * TPR + g) * N_NODE;
    const int*   rfb   = feature   + (size_t)(rb * TPR + g) * N_NODE;
    const float rootThV = rbase[0];                 // th[0]
    const float c0xV    = rbase[1];                 // th[1] (left child of root)
    const float c0yV    = rbase[2];                 // th[2] (right child of root)
    const int   rootFV  = rfb[0];
    const int   k0V     = (rfb[1] & 255) | ((rfb[2] & 255) << 8);

    // incremental per-round bases
    const float* tpre  = threshold + (size_t)(r0 * TPR + g) * N_NODE;
    const int*   fpre  = feature   + (size_t)(r0 * TPR + g) * N_NODE;
    const float* vbase = value + (size_t)(r0 * TPR + g) * N_NODE * N_OUTPUT;

    // ---- prefetch round-r0 records: dense coalesced (R9-identical) ----
    float thr[8]; int fr[8];
    #pragma unroll
    for (int j = 0; j < 8; ++j) { thr[j] = tpre[b + 64 * j]; fr[j] = fpre[b + 64 * j]; }

    // ---- stage x chunk transposed into LDS (conflict-free via XOR-swizzled R) ----
    {
        const float4* x4 = (const float4*)x;
        float4* R = (float4*)recbuf;                // 16 KB alias (pre-round only)
        #pragma unroll
        for (int rr = 0; rr < 2; ++rr) {
            #pragma unroll
            for (int k = 0; k < 2; ++k) {
                const int j  = tid + k * BLOCK;
                const int bl = j >> 5, f4 = j & 31;
                const int gb = chunk * BPB + rr * 32 + bl;
                float4 v = (gb < N_BATCH) ? x4[(size_t)gb * 32 + f4]
                                          : make_float4(0.f, 0.f, 0.f, 0.f);
                R[bl * 32 + (f4 ^ bl)] = v;
            }
            __syncthreads();
            {
                const int b32 = tid & 31, fc = tid >> 5;
                const int bb = rr * 32 + b32;
                #pragma unroll
                for (int c = 0; c < 2; ++c) {
                    const int f4 = fc * 2 + c;
                    float4 v = R[b32 * 32 + (f4 ^ b32)];
                    xt[(f4 * 4 + 0) * BPB + bb] = v.x;
                    xt[(f4 * 4 + 1) * BPB + bb] = v.y;
                    xt[(f4 * 4 + 2) * BPB + bb] = v.z;
                    xt[(f4 * 4 + 3) * BPB + bb] = v.w;
                }
            }
            __syncthreads();
        }
    }
    // No block barriers until the final reduction; each wave owns wbuf,
    // ordered by its own lgkmcnt waits.

    float acc[N_OUTPUT];
    #pragma unroll
    for (int o = 0; o < N_OUTPUT; ++o) acc[o] = 0.f;

    float*         thS = (float*)wbuf;
    unsigned char* fS  = (unsigned char*)(wbuf + 2048);

    for (int r = r0; r < r1; ++r) {
        __asm__ volatile("s_waitcnt lgkmcnt(0)" ::: "memory");   // WAR on wbuf
        #pragma unroll
        for (int j = 0; j < 8; ++j) {               // R9-identical shifted staging
            const int dst = (b + 64 * j - 1) & 511; // s=0 -> 511 (root)
            thS[dst] = thr[j];
            fS[dst]  = (unsigned char)fr[j];
        }
        __asm__ volatile("s_waitcnt lgkmcnt(0)" ::: "memory");   // RAW visibility

        if (r + 1 < r1) {                           // dense coalesced prefetch, next round
            const float* tn = tpre + TPR * N_NODE;
            const int*   fn = fpre + TPR * N_NODE;
            #pragma unroll
            for (int j = 0; j < 8; ++j) { thr[j] = tn[b + 64 * j]; fr[j] = fn[b + 64 * j]; }
            tpre = tn; fpre = fn;
        }

        // ---- traverse; round-r root state broadcast from registers (0 LDS) ----
        int n = 0;
        float th = __int_as_float(__builtin_amdgcn_readlane(__float_as_int(rootThV), r));
        int   fv = __builtin_amdgcn_readlane(rootFV, r);
        float cx = __int_as_float(__builtin_amdgcn_readlane(__float_as_int(c0xV), r));
        float cy = __int_as_float(__builtin_amdgcn_readlane(__float_as_int(c0yV), r));
        int   k  = __builtin_amdgcn_readlane(k0V, r);
        #pragma unroll
        for (int d = 0; d < DEPTH; ++d) {
            const float xv = xt[fv * BPB + b];      // only on-chain LDS read
            const int s = (xv > th) ? 1 : 0;        // xval <= split -> left
            n = 2 * n + 1 + s;
            if (d < DEPTH - 1) {
                th = s ? cy : cx;
                fv = (k >> (s << 3)) & 255;
            }
            if (d < DEPTH - 2) {                    // speculative pair (n <= 254)
                const float2 c = ((float2*)thS)[n]; // aligned ds_read_b64 @ 8n
                cx = c.x; cy = c.y;
                k = ((unsigned short*)fS)[n];       // aligned u16 @ 2n
            }
        }
        {
            const float4* vp = (const float4*)(vbase + (size_t)n * N_OUTPUT);
            const float4 a0 = vp[0], a1 = vp[1];
            acc[0] += a0.x; acc[1] += a0.y; acc[2] += a0.z; acc[3] += a0.w;
            acc[4] += a1.x; acc[5] += a1.y; acc[6] += a1.z; acc[7] += a1.w;
        }
        vbase += (size_t)TPR * N_NODE * N_OUTPUT;
    }

    // ---- reduce 8 waves' partials (alias recbuf, stride-9 pad) ----
    __syncthreads();
    float* red = (float*)recbuf;                    // 8*576*4 = 18432 <= 20480
    {
        float* dst = red + (g * 576 + b * 9);
        #pragma unroll
        for (int o = 0; o < N_OUTPUT; ++o) dst[o] = acc[o];
    }
    __syncthreads();
    {
        const int bl = tid >> 3, o = tid & 7;       // 512 threads = 64 batches x 8 outs
        const int bg = chunk * BPB + bl;
        float s = 0.f;
        #pragma unroll
        for (int gg = 0; gg < WAVES; ++gg) s += red[gg * 576 + bl * 9 + o];
        s *= (1.0f / N_TREE);
        if (!tail) {
            out[(size_t)chunk * (BPB * N_OUTPUT) + tid] = s;   // coalesced, exactly once
        } else if (bg < N_BATCH) {
            atomicAdd(out + (size_t)bg * N_OUTPUT + o, s);
        }
    }
}

extern "C" void kernel_launch(void* const* d_in, const int* in_sizes, int n_in,
                              void* d_out, int out_size, void* d_ws, size_t ws_size,
                              hipStream_t stream) {
    const float* x         = (const float*)d_in[0];
    const int*   feature   = (const int*)d_in[1];
    const float* threshold = (const float*)d_in[2];
    const float* value     = (const float*)d_in[5];   // children implied by complete heap layout
    float* out = (float*)d_out;

    // zero only the tail-chunk region (atomic accumulation); ~27 KB
    const size_t tail_off = (size_t)FULL_CHUNKS * BPB * N_OUTPUT;
    if ((size_t)out_size > tail_off) {
        hipMemsetAsync(out + tail_off, 0, ((size_t)out_size - tail_off) * sizeof(float), stream);
    }

    tree_kernel<<<dim3(GRID), dim3(BLOCK), 0, stream>>>(x, feature, threshold, value, out);
}

// Round 13
// 136.492 us; speedup vs baseline: 1.0636x; 1.0097x over previous
//
#include <hip/hip_runtime.h>

// ============================================================================
// LOCKED-IN BEST (R9 structure, best measured: 135.2 us total, ~69 us kernel)
// Design ledger (measured on MI355X):
//  - complete-tree: children = 2n+1/2n+2, children_left/right inputs unused
//  - xt transposed in LDS: gather bank = lane%32 -> conflict-free (R2: 3.9e7->4e5)
//  - no d_ws: harness poisons it 0xAA each call -> 128-212 MB L2/HBM churn (R4/R5)
//  - wave-private record buffers + lgkmcnt ordering, no barriers in K-loop (R6)
//  - 768 monolithic blocks + 14 chunks shattered into 25 round-blocks: kills
//    the 2x straggler phase (R7: 137->100 us)
//  - shifted heap copy thS[k]=th[k+1]: speculative child-pair = 1 aligned
//    ds_read_b64, dense coalesced prefetch (R8: 100->73.5)
//  - 8 waves x 1 tree: 24 waves/CU at same LDS (R9: ~69)
//  - REJECTED by measurement: ds_write_b64 staging (bank conflicts, R10),
//    u16-pair feature staging (strided prefetch TA, R11), roots-in-regs (parity, R12)
// ============================================================================

#define N_BATCH   50000
#define N_FEATURE 128
#define DEPTH     9
#define N_TREE    200
#define N_NODE    1023
#define N_OUTPUT  8

#define BPB     64                            // batches per block (lanes)
#define WAVES   8
#define BLOCK   (WAVES * 64)                  // 512 threads
#define TPR     8                             // trees per round (1 per wave)
#define ROUNDS  (N_TREE / TPR)                // 25

#define FULL_CHUNKS 768
#define NCHUNK      ((N_BATCH + BPB - 1) / BPB)     // 782
#define TAIL_CHUNKS (NCHUNK - FULL_CHUNKS)          // 14
#define TAIL_SPLIT  ROUNDS
#define TAIL_BLOCKS (TAIL_CHUNKS * TAIL_SPLIT)      // 350
#define GRID        (FULL_CHUNKS + TAIL_BLOCKS)     // 1118

// Per-wave private buffer, 1 tree (2560 B): shifted heap copy
//   thS[k] = th[k+1] (k=0..510), thS[511] = th[0] (root)   [2048 B]
//   fS[k]  = feat[k+1] u8,       fS[511]  = root feat      [512 B]
// pair(n) = float2 @ thS[2n] (8B aligned), fpair(n) = u16 @ fS[2n].
#define TREE_B  2560
#define REC_B   (WAVES * TREE_B)              // 20480

__global__ __launch_bounds__(BLOCK, 6)        // 3 blocks/CU (LDS-capped), 24 waves/CU
void tree_kernel(const float* __restrict__ x,
                 const int*   __restrict__ feature,
                 const float* __restrict__ threshold,
                 const float* __restrict__ value,
                 float*       __restrict__ out)
{
    __shared__ float xt[N_FEATURE * BPB];           // 32 KB, xt[f*64+b]: bank = lane%32 (free)
    __shared__ __align__(16) char recbuf[REC_B];    // 20 KB, 8 wave-private slices

    const int tid = threadIdx.x;
    const int bid = blockIdx.x;
    const int b   = tid & 63;                       // lane = batch within chunk
    const int g   = tid >> 6;                       // wave id: tree g of each round
    char* wbuf = recbuf + g * TREE_B;

    int chunk, r0, r1; bool tail;
    if (bid < FULL_CHUNKS) { chunk = bid; r0 = 0; r1 = ROUNDS; tail = false; }
    else {
        const int t2 = bid - FULL_CHUNKS;
        chunk = FULL_CHUNKS + t2 / TAIL_SPLIT;
        r0 = t2 % TAIL_SPLIT; r1 = r0 + 1; tail = true;
    }

    // incremental per-round bases (avoid 64-bit muls in the loop)
    const float* tpre = threshold + (size_t)(r0 * TPR + g) * N_NODE + b;
    const int*   fpre = feature   + (size_t)(r0 * TPR + g) * N_NODE + b;
    const float* vbase = value + (size_t)(r0 * TPR + g) * N_NODE * N_OUTPUT;

    // ---- prefetch round-r0 records (dense coalesced, imm-offset friendly) ----
    float thr[8]; int fr[8];
    #pragma unroll
    for (int j = 0; j < 8; ++j) { thr[j] = tpre[j * 64]; fr[j] = fpre[j * 64]; }

    // ---- stage x chunk transposed into LDS (conflict-free via XOR-swizzled R) ----
    {
        const float4* x4 = (const float4*)x;
        float4* R = (float4*)recbuf;                // 16 KB alias (pre-round only)
        #pragma unroll
        for (int rr = 0; rr < 2; ++rr) {
            #pragma unroll
            for (int k = 0; k < 2; ++k) {           // 1024 float4 / 512 thr = 2 iters
                const int j  = tid + k * BLOCK;
                const int bl = j >> 5, f4 = j & 31;
                const int gb = chunk * BPB + rr * 32 + bl;
                float4 v = (gb < N_BATCH) ? x4[(size_t)gb * 32 + f4]
                                          : make_float4(0.f, 0.f, 0.f, 0.f);
                R[bl * 32 + (f4 ^ bl)] = v;
            }
            __syncthreads();
            {
                const int b32 = tid & 31, fc = tid >> 5;   // fc = 0..15
                const int bb = rr * 32 + b32;
                #pragma unroll
                for (int c = 0; c < 2; ++c) {
                    const int f4 = fc * 2 + c;
                    float4 v = R[b32 * 32 + (f4 ^ b32)];
                    xt[(f4 * 4 + 0) * BPB + bb] = v.x;
                    xt[(f4 * 4 + 1) * BPB + bb] = v.y;
                    xt[(f4 * 4 + 2) * BPB + bb] = v.z;
                    xt[(f4 * 4 + 3) * BPB + bb] = v.w;
                }
            }
            __syncthreads();
        }
    }
    // No block barriers from here until the final reduction: each wave owns
    // wbuf exclusively, ordered by its own lgkmcnt waits.

    float acc[N_OUTPUT];
    #pragma unroll
    for (int o = 0; o < N_OUTPUT; ++o) acc[o] = 0.f;

    float*         thS = (float*)wbuf;
    unsigned char* fS  = (unsigned char*)(wbuf + 2048);

    for (int r = r0; r < r1; ++r) {
        __asm__ volatile("s_waitcnt lgkmcnt(0)" ::: "memory");   // WAR on wbuf
        #pragma unroll
        for (int j = 0; j < 8; ++j) {               // shifted copy, branchless dst
            const int dst = (b + j * 64 - 1) & 511; // s=0 -> 511 (root)
            thS[dst] = thr[j];
            fS[dst]  = (unsigned char)fr[j];
        }
        __asm__ volatile("s_waitcnt lgkmcnt(0)" ::: "memory");   // RAW visibility

        if (r + 1 < r1) {                           // dense coalesced prefetch, next round
            const float* tn = tpre + TPR * N_NODE;
            const int*   fn = fpre + TPR * N_NODE;
            #pragma unroll
            for (int j = 0; j < 8; ++j) { thr[j] = tn[j * 64]; fr[j] = fn[j * 64]; }
            tpre = tn; fpre = fn;
        }

        // ---- traverse 1 tree; next record selected from regs (1 LDS lat/level) ----
        int n = 0;
        float th = thS[511];                        // root
        int   fv = fS[511];
        float2 c = ((float2*)thS)[0];               // children of root
        int   k  = ((unsigned short*)fS)[0];
        #pragma unroll
        for (int d = 0; d < DEPTH; ++d) {
            const float xv = xt[fv * BPB + b];      // only on-chain LDS read
            const int s = (xv > th) ? 1 : 0;        // xval <= split -> left
            n = 2 * n + 1 + s;
            if (d < DEPTH - 1) {
                th = s ? c.y : c.x;
                fv = (k >> (s << 3)) & 255;
            }
            if (d < DEPTH - 2) {                    // speculative pair read (n <= 254)
                c = ((float2*)thS)[n];
                k = ((unsigned short*)fS)[n];
            }
        }
        {
            const float4* vp = (const float4*)(vbase + (size_t)n * N_OUTPUT);
            const float4 a0 = vp[0], a1 = vp[1];
            acc[0] += a0.x; acc[1] += a0.y; acc[2] += a0.z; acc[3] += a0.w;
            acc[4] += a1.x; acc[5] += a1.y; acc[6] += a1.z; acc[7] += a1.w;
        }
        vbase += (size_t)TPR * N_NODE * N_OUTPUT;
    }

    // ---- reduce 8 waves' partials (alias recbuf, stride-9 pad) ----
    __syncthreads();
    float* red = (float*)recbuf;                    // 8*576*4 = 18432 <= 20480
    {
        float* dst = red + (g * 576 + b * 9);
        #pragma unroll
        for (int o = 0; o < N_OUTPUT; ++o) dst[o] = acc[o];
    }
    __syncthreads();
    {
        const int bl = tid >> 3, o = tid & 7;       // 512 threads = 64 batches x 8 outs
        const int bg = chunk * BPB + bl;
        float s = 0.f;
        #pragma unroll
        for (int gg = 0; gg < WAVES; ++gg) s += red[gg * 576 + bl * 9 + o];
        s *= (1.0f / N_TREE);
        if (!tail) {
            out[(size_t)chunk * (BPB * N_OUTPUT) + tid] = s;   // coalesced, exactly once
        } else if (bg < N_BATCH) {
            atomicAdd(out + (size_t)bg * N_OUTPUT + o, s);
        }
    }
}

extern "C" void kernel_launch(void* const* d_in, const int* in_sizes, int n_in,
                              void* d_out, int out_size, void* d_ws, size_t ws_size,
                              hipStream_t stream) {
    const float* x         = (const float*)d_in[0];
    const int*   feature   = (const int*)d_in[1];
    const float* threshold = (const float*)d_in[2];
    const float* value     = (const float*)d_in[5];   // children implied by complete heap layout
    float* out = (float*)d_out;

    // zero only the tail-chunk region (atomic accumulation); ~27 KB
    const size_t tail_off = (size_t)FULL_CHUNKS * BPB * N_OUTPUT;
    if ((size_t)out_size > tail_off) {
        hipMemsetAsync(out + tail_off, 0, ((size_t)out_size - tail_off) * sizeof(float), stream);
    }

    tree_kernel<<<dim3(GRID), dim3(BLOCK), 0, stream>>>(x, feature, threshold, value, out);
}